// Round 9
// baseline (175.066 us; speedup 1.0000x reference)
//
#include <hip/hip_runtime.h>
#include <hip/hip_bf16.h>
#include <math.h>

#define Bb 2
#define Lq 384
#define Sk 384
#define Dd 512
#define Hh 256

#define LIST_CAP 65536

// workspace layout (bytes) — f64 regions first for 8B alignment
#define HQD_OFF  0                                   // B*L*H doubles = 1572864
#define HKD_OFF  (HQD_OFF + Bb*Lq*Hh*8)              // B*S*H doubles = 1572864
#define HQ_OFF   (HKD_OFF + Bb*Sk*Hh*8)              // B*L*H floats = 786432
#define HK_OFF   (HQ_OFF + Bb*Lq*Hh*4)               // B*S*H floats
#define SIM0_OFF (HK_OFF + Bb*Sk*Hh*4)               // B*L*S floats = 1179648
#define SIM1_OFF (SIM0_OFF + Bb*Lq*Sk*4)             // B*L*S floats
#define SCAL_OFF (SIM1_OFF + Bb*Lq*Sk*4)             // 2 floats
#define CNT_OFF  (SCAL_OFF + 64)                     // 1 int
#define LIST_OFF (CNT_OFF + 64)                      // LIST_CAP ints

// ---------------------------------------------------------------------------
// projd: 192 blocks x 512 threads. Block = 8 rows of one (tensor,b); thread
// = (h, d-half). Fused: per-thread f64 global-vector dot on its d-half
// (merged via the same LDS exchange), so no separate globald dispatch.
// Block 0 additionally: zeroes cnt; wave 0 computes scal={gwsum,bconst}
// via an intra-wave shuffle reduction (NO block-level barriers involved —
// a divergent s_barrier here was the R8 correctness bug).
//   hq_d = q@Wq + qg@Wqg   (f64; b1 NOT included — cleanup adds it)
//   hq   = (float)(hq_d + b1)      [k-side: no b1]
__global__ __launch_bounds__(512) void projd_kernel(
    const float* __restrict__ q, const float* __restrict__ k,
    const float* __restrict__ qg, const float* __restrict__ kg,
    const float* __restrict__ W1, const float* __restrict__ b1,
    const float* __restrict__ gam, const float* __restrict__ bet,
    const float* __restrict__ W2, const float* __restrict__ b2,
    double* __restrict__ hq_d, double* __restrict__ hk_d,
    float* __restrict__ hq, float* __restrict__ hk,
    float* __restrict__ scal, int* __restrict__ cnt)
{
    __shared__ __align__(16) double sbuf[9 * 256];       // 18 KB
    float  (*tile)[512] = (float (*)[512])sbuf;          // 8x512 f32 (16 KB)
    float*  gvd  = (float*)(sbuf + 2048);                // 512 f32 (2 KB)
    double (*pbuf)[256] = (double (*)[256])sbuf;         // alias after compute
    double* gbuf = sbuf + 2048;                          // alias after compute

    int tid = threadIdx.x;
    int h   = tid & 255;
    int dh  = tid >> 8;                                  // 0/1
    int bx = blockIdx.x;                                 // 0..191
    bool isQ = bx < 96;
    int bb = isQ ? bx : bx - 96;
    int b  = bb / 48;
    int rg = bb % 48;
    const float* src = isQ ? q : k;
    const float* gl  = isQ ? qg : kg;
    int woff  = isQ ? 0 : Dd * Hh;
    int woffg = isQ ? 2 * Dd * Hh : 3 * Dd * Hh;
    double* dstd = isQ ? hq_d : hk_d;
    float*  dstf = isQ ? hq : hk;

    if (bx == 0 && tid == 0) *cnt = 0;
    if (bx == 0 && tid < 64) {
        // wave-0-only scal reduction: 4 h-values per lane, shuffle butterfly.
        float a = 0.f, c = 0.f;
        for (int i = tid; i < 256; i += 64) {
            float w2v = W2[i];
            a = fmaf(gam[i], w2v, a);
            c = fmaf(bet[i], w2v, c);
        }
        for (int o = 32; o > 0; o >>= 1) {
            a += __shfl_xor(a, o, 64);
            c += __shfl_xor(c, o, 64);
        }
        if (tid == 0) { scal[0] = a; scal[1] = c + b2[0]; }
    }

    int base = (b * Lq + rg * 8) * Dd;
    for (int i = tid; i < 1024; i += 512)
        *reinterpret_cast<float4*>((float*)tile + i * 4) =
            *reinterpret_cast<const float4*>(src + base + i * 4);
    if (tid < 128)
        *reinterpret_cast<float4*>(gvd + tid * 4) =
            *reinterpret_cast<const float4*>(gl + b * Dd + tid * 4);
    __syncthreads();

    const float* wp = W1 + woff  + (dh * 256) * Hh + h;
    const float* gp = W1 + woffg + (dh * 256) * Hh + h;
    int dbase = dh * 256;
    double acc[8];
#pragma unroll
    for (int r = 0; r < 8; ++r) acc[r] = 0.0;
    double gacc = 0.0;
#pragma unroll 2
    for (int d4 = 0; d4 < 256; d4 += 4) {
        double w0 = (double)wp[(d4 + 0) * Hh];
        double w1 = (double)wp[(d4 + 1) * Hh];
        double w2 = (double)wp[(d4 + 2) * Hh];
        double w3 = (double)wp[(d4 + 3) * Hh];
        float4 gv = *reinterpret_cast<const float4*>(&gvd[dbase + d4]);
        gacc = fma((double)gv.x, (double)gp[(d4 + 0) * Hh], gacc);
        gacc = fma((double)gv.y, (double)gp[(d4 + 1) * Hh], gacc);
        gacc = fma((double)gv.z, (double)gp[(d4 + 2) * Hh], gacc);
        gacc = fma((double)gv.w, (double)gp[(d4 + 3) * Hh], gacc);
#pragma unroll
        for (int r = 0; r < 8; ++r) {
            float4 tv = *reinterpret_cast<const float4*>(&tile[r][dbase + d4]);
            acc[r] = fma((double)tv.x, w0, acc[r]);
            acc[r] = fma((double)tv.y, w1, acc[r]);
            acc[r] = fma((double)tv.z, w2, acc[r]);
            acc[r] = fma((double)tv.w, w3, acc[r]);
        }
    }
    __syncthreads();                 // tile/gvd reads complete
    if (dh == 1) {
#pragma unroll
        for (int r = 0; r < 8; ++r) pbuf[r][h] = acc[r];
        gbuf[h] = gacc;
    }
    __syncthreads();
    if (dh == 0) {
        double gd  = gacc + gbuf[h];             // full global dot
        double b1d = isQ ? (double)b1[h] : 0.0;
        int ob = (b * Lq + rg * 8) * Hh + h;
#pragma unroll
        for (int r = 0; r < 8; ++r) {
            double tot = (acc[r] + pbuf[r][h]) + gd;
            dstd[ob + r * Hh] = tot;
            dstf[ob + r * Hh] = (float)(tot + b1d);
        }
    }
}

// ---------------------------------------------------------------------------
// sim: 32x32 tile, 2x2 per thread, float4 inner reads, K split in 2 halves.
__global__ __launch_bounds__(256) void sim_kernel(
    const float* __restrict__ q, const float* __restrict__ k,
    float* __restrict__ sim01)
{
    __shared__ __align__(16) float qs[32][132];
    __shared__ __align__(16) float ks[32][132];
    int tid = threadIdx.x;
    int bx = blockIdx.x;
    int kc = (bx >= Bb * 144) ? 1 : 0;
    int r  = bx - kc * Bb * 144;
    int b  = r / 144;  r %= 144;
    int lt = r / 12, st = r % 12;
    int tl = tid >> 4, ts = tid & 15;
    const float* qb = q + (b * Lq + lt * 32) * Dd;
    const float* kb = k + (b * Sk + st * 32) * Dd;
    float a00 = 0.f, a01 = 0.f, a10 = 0.f, a11 = 0.f;
    for (int c = kc * 256; c < kc * 256 + 256; c += 128) {
        __syncthreads();
        for (int i = tid; i < 1024; i += 256) {
            int row = i >> 5;
            int c4  = (i & 31) << 2;
            *reinterpret_cast<float4*>(&qs[row][c4]) =
                *reinterpret_cast<const float4*>(qb + row * Dd + c + c4);
            *reinterpret_cast<float4*>(&ks[row][c4]) =
                *reinterpret_cast<const float4*>(kb + row * Dd + c + c4);
        }
        __syncthreads();
#pragma unroll 2
        for (int dd = 0; dd < 128; dd += 4) {
            float4 q0 = *reinterpret_cast<const float4*>(&qs[tl][dd]);
            float4 q1 = *reinterpret_cast<const float4*>(&qs[tl + 16][dd]);
            float4 k0 = *reinterpret_cast<const float4*>(&ks[ts][dd]);
            float4 k1 = *reinterpret_cast<const float4*>(&ks[ts + 16][dd]);
            a00 = fmaf(q0.x, k0.x, a00); a00 = fmaf(q0.y, k0.y, a00);
            a00 = fmaf(q0.z, k0.z, a00); a00 = fmaf(q0.w, k0.w, a00);
            a01 = fmaf(q0.x, k1.x, a01); a01 = fmaf(q0.y, k1.y, a01);
            a01 = fmaf(q0.z, k1.z, a01); a01 = fmaf(q0.w, k1.w, a01);
            a10 = fmaf(q1.x, k0.x, a10); a10 = fmaf(q1.y, k0.y, a10);
            a10 = fmaf(q1.z, k0.z, a10); a10 = fmaf(q1.w, k0.w, a10);
            a11 = fmaf(q1.x, k1.x, a11); a11 = fmaf(q1.y, k1.y, a11);
            a11 = fmaf(q1.z, k1.z, a11); a11 = fmaf(q1.w, k1.w, a11);
        }
    }
    const float sc = 0.04419417382415922f;          // 1/sqrt(512)
    float* dst = sim01 + kc * (Bb * Lq * Sk);
    int l0 = lt * 32 + tl, s0 = st * 32 + ts;
    dst[(b * Lq + l0)      * Sk + s0]      = a00 * sc;
    dst[(b * Lq + l0)      * Sk + s0 + 16] = a01 * sc;
    dst[(b * Lq + l0 + 16) * Sk + s0]      = a10 * sc;
    dst[(b * Lq + l0 + 16) * Sk + s0 + 16] = a11 * sc;
}

// ---------------------------------------------------------------------------
// packed-pair gelu accumulate: y2 = 2*gelu(x); sums fold the 0.5 later.
__device__ __forceinline__ void gelu2(float2 hqv, float2 hkv, float2 gwv,
                                      float2& s1, float2& s2, float2& sw)
{
    const float P2   = 0.23164189f;            // 0.3275911/sqrt(2)
    const float A1f = 0.254829592f, A2f = -0.284496736f, A3f = 1.421413741f,
                A4f = -1.453152027f, A5f = 1.061405429f;
    const float NL2EH = -0.72134752044448170f; // -log2(e)/2

    float xa = hqv.x + hkv.x,        xb = hqv.y + hkv.y;
    float axa = fabsf(xa),           axb = fabsf(xb);
    float dda = fmaf(P2, axa, 1.0f), ddb = fmaf(P2, axb, 1.0f);
    float ta = __builtin_amdgcn_rcpf(dda), tb = __builtin_amdgcn_rcpf(ddb);
    float x2a = xa * xa,             x2b = xb * xb;
    float exa = __builtin_amdgcn_exp2f(x2a * NL2EH);
    float exb = __builtin_amdgcn_exp2f(x2b * NL2EH);
    float sa = fmaf(A5f, ta, A4f),   sb = fmaf(A5f, tb, A4f);
    sa = fmaf(sa, ta, A3f);          sb = fmaf(sb, tb, A3f);
    sa = fmaf(sa, ta, A2f);          sb = fmaf(sb, tb, A2f);
    sa = fmaf(sa, ta, A1f);          sb = fmaf(sb, tb, A1f);
    sa = sa * ta;                    sb = sb * tb;
    float Ea = fmaf(-sa, exa, 1.0f), Eb = fmaf(-sb, exb, 1.0f);
    float ya = fmaf(axa, Ea, xa),    yb = fmaf(axb, Eb, xb);   // = 2*gelu
    s1.x += ya;                      s1.y += yb;
    s2.x = fmaf(ya, ya, s2.x);       s2.y = fmaf(yb, yb, s2.y);
    sw.x = fmaf(ya, gwv.x, sw.x);    sw.y = fmaf(yb, gwv.y, sw.y);
}

// ---------------------------------------------------------------------------
// main: 32x16 (l,s) tile per 256-thread block; each thread 2 l-rows x 1 s.
// 2x1 blocking shares the hk/gw LDS reads across two outputs.
__global__ __launch_bounds__(256) void main_kernel(
    const float* __restrict__ hq, const float* __restrict__ hk,
    const float* __restrict__ sim0, const float* __restrict__ sim1,
    const float* __restrict__ gam, const float* __restrict__ W2,
    const float* __restrict__ scal,
    const float* __restrict__ gu, float* __restrict__ out,
    int* __restrict__ cnt, int* __restrict__ list)
{
    __shared__ __align__(16) float hq_t[32][260];
    __shared__ __align__(16) float hk_t[16][260];
    __shared__ __align__(16) float gw_s[256];
    int tid = threadIdx.x;
    int bx = blockIdx.x;
    int b  = bx / (12 * 24);
    int r  = bx % (12 * 24);
    int lt = r / 24, st = r % 24;          // l-tile 32 rows, s-tile 16 cols

    const float* hqb = hq + (b * Lq + lt * 32) * Hh;
    const float* hkb = hk + (b * Sk + st * 16) * Hh;
#pragma unroll
    for (int i = 0; i < 8; ++i) {          // 32 rows x 64 float4
        int idx4 = i * 256 + tid;
        int row  = idx4 >> 6;
        int col4 = (idx4 & 63) << 2;
        *reinterpret_cast<float4*>(&hq_t[row][col4]) =
            *reinterpret_cast<const float4*>(hqb + row * Hh + col4);
    }
#pragma unroll
    for (int i = 0; i < 4; ++i) {          // 16 rows x 64 float4
        int idx4 = i * 256 + tid;
        int row  = idx4 >> 6;
        int col4 = (idx4 & 63) << 2;
        *reinterpret_cast<float4*>(&hk_t[row][col4]) =
            *reinterpret_cast<const float4*>(hkb + row * Hh + col4);
    }
    gw_s[tid] = gam[tid] * W2[tid];
    __syncthreads();
    float gwsum  = scal[0];
    float bconst = scal[1];

    int tl = tid >> 4, ts = tid & 15;
    float2 s1a = make_float2(0.f, 0.f), s2a = s1a, swa = s1a;
    float2 s1b = s1a, s2b = s1a, swb = s1a;
#pragma unroll 2
    for (int h4 = 0; h4 < Hh; h4 += 4) {
        float4 ha = *reinterpret_cast<const float4*>(&hq_t[tl][h4]);
        float4 hb = *reinterpret_cast<const float4*>(&hq_t[tl + 16][h4]);
        float4 kk = *reinterpret_cast<const float4*>(&hk_t[ts][h4]);
        float4 g4 = *reinterpret_cast<const float4*>(&gw_s[h4]);
        gelu2(make_float2(ha.x, ha.y), make_float2(kk.x, kk.y),
              make_float2(g4.x, g4.y), s1a, s2a, swa);
        gelu2(make_float2(ha.z, ha.w), make_float2(kk.z, kk.w),
              make_float2(g4.z, g4.w), s1a, s2a, swa);
        gelu2(make_float2(hb.x, hb.y), make_float2(kk.x, kk.y),
              make_float2(g4.x, g4.y), s1b, s2b, swb);
        gelu2(make_float2(hb.z, hb.w), make_float2(kk.z, kk.w),
              make_float2(g4.z, g4.w), s1b, s2b, swb);
    }

#pragma unroll
    for (int e = 0; e < 2; ++e) {
        float S1 = e ? (s1b.x + s1b.y) : (s1a.x + s1a.y);
        float S2 = e ? (s2b.x + s2b.y) : (s2a.x + s2a.y);
        float SW = 0.5f * (e ? (swb.x + swb.y) : (swa.x + swa.y));
        float mu   = S1 * (1.0f / 512.0f);
        float var  = S2 * (1.0f / 1024.0f) - mu * mu;
        float rstd = rsqrtf(var + 1e-5f);
        float thr  = rstd * (SW - mu * gwsum) + bconst;

        int l = lt * 32 + tl + e * 16, s = st * 16 + ts;
        int idx = (b * Lq + l) * Sk + s;
        float  sv = sim0[idx] + sim1[idx];
        float2 uv = reinterpret_cast<const float2*>(gu)[idx];
        float u0 = fminf(fmaxf(uv.x, 1e-6f), 1.0f - 1e-6f);
        float u1 = fminf(fmaxf(uv.y, 1e-6f), 1.0f - 1e-6f);
        float g0 = -logf(-logf(u0));
        float g1 = -logf(-logf(u1));
        float t  = 0.2f * (sv - thr) + (g1 - g0);
        out[idx] = t > 0.0f ? 1.0f : 0.0f;
        if (fabsf(t) < 1e-3f) {
            int p = atomicAdd(cnt, 1);
            if (p < LIST_CAP) list[p] = idx;
        }
    }
}

// ---------------------------------------------------------------------------
// cleanup: per flagged item, f64 finish using precomputed f64 projections.
__global__ __launch_bounds__(256) void cleanup_kernel(
    const float* __restrict__ q, const float* __restrict__ k,
    const double* __restrict__ hq_d, const double* __restrict__ hk_d,
    const float* __restrict__ b1,
    const float* __restrict__ gam, const float* __restrict__ bet,
    const float* __restrict__ W2, const float* __restrict__ b2,
    const float* __restrict__ gu, float* __restrict__ out,
    const int* __restrict__ cnt, const int* __restrict__ list)
{
    __shared__ double s0[256], s1[256], s2[256], s3[256];
    int tid = threadIdx.x;
    int n = *cnt;
    if (n > LIST_CAP) n = LIST_CAP;
    if (n == 0) return;

    double gw  = (double)gam[tid] * (double)W2[tid];
    double b1d = (double)b1[tid];
    s0[tid] = (double)bet[tid] * (double)W2[tid];
    s1[tid] = gw;
    __syncthreads();
    for (int o = 128; o > 0; o >>= 1) {
        if (tid < o) { s0[tid] += s0[tid + o]; s1[tid] += s1[tid + o]; }
        __syncthreads();
    }
    double bconst = s0[0] + (double)b2[0];
    double gwsum  = s1[0];
    __syncthreads();

    for (int it = blockIdx.x; it < n; it += gridDim.x) {
        int idx = list[it];
        int b   = idx / (Lq * Sk);
        int rem = idx % (Lq * Sk);
        int l = rem / Sk, s = rem % Sk;
        double x = (hq_d[(b * Lq + l) * Hh + tid]
                  + hk_d[(b * Sk + s) * Hh + tid]) + b1d;
        double y = 0.5 * x * (1.0 + erf(x * 0.70710678118654752440));
        const float* qrow = q + (b * Lq + l) * Dd;
        const float* krow = k + (b * Sk + s) * Dd;
        double sp = (double)qrow[tid] * (double)krow[tid]
                  + (double)qrow[tid + 256] * (double)krow[tid + 256];
        s0[tid] = y; s1[tid] = y * y; s2[tid] = y * gw; s3[tid] = sp;
        __syncthreads();
        for (int o = 128; o > 0; o >>= 1) {
            if (tid < o) {
                s0[tid] += s0[tid + o]; s1[tid] += s1[tid + o];
                s2[tid] += s2[tid + o]; s3[tid] += s3[tid + o];
            }
            __syncthreads();
        }
        if (tid == 0) {
            double mu   = s0[0] * (1.0 / 256.0);
            double var  = s1[0] * (1.0 / 256.0) - mu * mu;
            double rstd = 1.0 / sqrt(var + 1e-5);
            double thr  = rstd * (s2[0] - mu * gwsum) + bconst;
            double simv = s3[0] / 22.627416997969522;   // sqrt(512)
            float2 uv = reinterpret_cast<const float2*>(gu)[idx];
            double u0 = fmin(fmax((double)uv.x, 1e-6), 1.0 - 1e-6);
            double u1 = fmin(fmax((double)uv.y, 1e-6), 1.0 - 1e-6);
            double g0 = -log(-log(u0));
            double g1 = -log(-log(u1));
            double t  = 0.2 * (simv - thr) + (g1 - g0);
            out[idx] = t > 0.0 ? 1.0f : 0.0f;
        }
        __syncthreads();
    }
}

// ---------------------------------------------------------------------------
extern "C" void kernel_launch(void* const* d_in, const int* in_sizes, int n_in,
                              void* d_out, int out_size, void* d_ws, size_t ws_size,
                              hipStream_t stream)
{
    const float* q   = (const float*)d_in[0];
    const float* k   = (const float*)d_in[1];
    const float* qg  = (const float*)d_in[2];
    const float* kg  = (const float*)d_in[3];
    const float* W1  = (const float*)d_in[4];
    const float* b1  = (const float*)d_in[5];
    const float* gam = (const float*)d_in[6];
    const float* bet = (const float*)d_in[7];
    const float* W2  = (const float*)d_in[8];
    const float* b2  = (const float*)d_in[9];
    const float* gu  = (const float*)d_in[10];
    float* out = (float*)d_out;

    char*   ws   = (char*)d_ws;
    double* hq_d = (double*)(ws + HQD_OFF);
    double* hk_d = (double*)(ws + HKD_OFF);
    float*  hq   = (float*)(ws + HQ_OFF);
    float*  hk   = (float*)(ws + HK_OFF);
    float*  sim0 = (float*)(ws + SIM0_OFF);
    float*  sim1 = (float*)(ws + SIM1_OFF);
    float*  scal = (float*)(ws + SCAL_OFF);
    int*    cnt  = (int*)(ws + CNT_OFF);
    int*    list = (int*)(ws + LIST_OFF);

    projd_kernel<<<192, 512, 0, stream>>>(
        q, k, qg, kg, W1, b1, gam, bet, W2, b2,
        hq_d, hk_d, hq, hk, scal, cnt);
    sim_kernel<<<2 * Bb * 144, 256, 0, stream>>>(q, k, sim0);
    main_kernel<<<Bb * 12 * 24, 256, 0, stream>>>(
        hq, hk, sim0, sim1, gam, W2, scal, gu, out, cnt, list);
    cleanup_kernel<<<768, 256, 0, stream>>>(
        q, k, hq_d, hk_d, b1, gam, bet, W2, b2, gu, out, cnt, list);
}

// Round 10
// 171.112 us; speedup vs baseline: 1.0231x; 1.0231x over previous
//
#include <hip/hip_runtime.h>
#include <hip/hip_bf16.h>
#include <math.h>

#define Bb 2
#define Lq 384
#define Sk 384
#define Dd 512
#define Hh 256

#define LIST_CAP 65536
#define NROWS (2 * Bb * Lq)          // 1536 total rows (q then k)

// workspace layout (bytes) — f64 regions first for 8B alignment
#define HQD_OFF  0                                   // B*L*H doubles = 1572864
#define HKD_OFF  (HQD_OFF + Bb*Lq*Hh*8)              // B*S*H doubles
#define PART_OFF (HKD_OFF + Bb*Sk*Hh*8)              // 1536*4*256 doubles = 12.6MB
#define GQD_OFF  (PART_OFF + NROWS*4*Hh*8)
#define GKD_OFF  (GQD_OFF + Bb*Hh*8)
#define HQ_OFF   (GKD_OFF + Bb*Hh*8)                 // B*L*H floats
#define HK_OFF   (HQ_OFF + Bb*Lq*Hh*4)               // B*S*H floats
#define SIM0_OFF (HK_OFF + Bb*Sk*Hh*4)               // B*L*S floats
#define SIM1_OFF (SIM0_OFF + Bb*Lq*Sk*4)             // B*L*S floats
#define SCAL_OFF (SIM1_OFF + Bb*Lq*Sk*4)             // 2 floats
#define CNT_OFF  (SCAL_OFF + 64)                     // 1 int
#define LIST_OFF (CNT_OFF + 64)                      // LIST_CAP ints

// ---------------------------------------------------------------------------
// smalls: bx<16 -> f64 global-vector projections (gq_d, gk_d);
//         bx==16 -> scal={gwsum, bconst}, cnt=0.
__global__ __launch_bounds__(256) void smalls_kernel(
    const float* __restrict__ qg, const float* __restrict__ kg,
    const float* __restrict__ W1,
    const float* __restrict__ gam, const float* __restrict__ bet,
    const float* __restrict__ W2, const float* __restrict__ b2,
    double* __restrict__ gq_d, double* __restrict__ gk_d,
    float* __restrict__ scal, int* __restrict__ cnt)
{
    __shared__ double red[64][5];
    __shared__ float2 red2[256];
    int bx  = blockIdx.x;
    int tid = threadIdx.x;
    if (bx < 16) {
        int isK = bx & 1;
        int b   = (bx >> 1) & 1;
        int hc  = bx >> 2;                  // 0..3
        int hl  = tid >> 2;                 // 0..63
        int dp  = tid & 3;                  // 0..3
        int h   = hc * 64 + hl;
        const float* gv = (isK ? kg : qg) + b * Dd;
        const float* wp = W1 + (isK ? 3 : 2) * Dd * Hh + h;
        int d0 = dp * 128;
        double a0 = 0, a1 = 0, a2 = 0, a3 = 0;
        for (int i = 0; i < 128; i += 4) {
            int d = d0 + i;
            a0 = fma((double)gv[d + 0], (double)wp[(d + 0) * Hh], a0);
            a1 = fma((double)gv[d + 1], (double)wp[(d + 1) * Hh], a1);
            a2 = fma((double)gv[d + 2], (double)wp[(d + 2) * Hh], a2);
            a3 = fma((double)gv[d + 3], (double)wp[(d + 3) * Hh], a3);
        }
        red[hl][dp] = ((a0 + a1) + (a2 + a3));
        __syncthreads();
        if (dp == 0) {
            double s = (red[hl][0] + red[hl][1]) + (red[hl][2] + red[hl][3]);
            (isK ? gk_d : gq_d)[b * Hh + h] = s;
        }
    } else {
        if (tid == 0) *cnt = 0;
        float w2v = W2[tid];
        red2[tid] = make_float2(gam[tid] * w2v, bet[tid] * w2v);
        __syncthreads();
        for (int o = 128; o > 0; o >>= 1) {
            if (tid < o) {
                red2[tid].x += red2[tid + o].x;
                red2[tid].y += red2[tid + o].y;
            }
            __syncthreads();
        }
        if (tid == 0) {
            scal[0] = red2[0].x;
            scal[1] = red2[0].y + b2[0];
        }
    }
}

// ---------------------------------------------------------------------------
// projd_part: f64 row-projection partials. Block = 4 rows x one 128-d slice,
// 256 threads (h). Grid 1536 = 384 row-groups x 4 d-slices -> 6 blocks/CU,
// 6 waves/SIMD (fixes the 1.5-waves/SIMD latency exposure of R9).
// part[rowglob][ds][h] = sum_{d in slice} src[row][d] * W[d][h]   (f64)
__global__ __launch_bounds__(256) void projd_part_kernel(
    const float* __restrict__ q, const float* __restrict__ k,
    const float* __restrict__ W1, double* __restrict__ part)
{
    __shared__ __align__(16) float tile[4][128];      // 2 KB
    int tid = threadIdx.x;
    int bx  = blockIdx.x;                             // 0..1535
    int ds  = bx & 3;                                 // d-slice 0..3
    int rgid = bx >> 2;                               // 0..383
    bool isQ = rgid < 192;
    int bb = isQ ? rgid : rgid - 192;
    int b  = bb / 96;
    int rg = bb % 96;                                 // 4-row group
    const float* src = isQ ? q : k;
    int woff = isQ ? 0 : Dd * Hh;
    int rowbase = b * Lq + rg * 4;

    if (tid < 128) {
        int row = tid >> 5;                           // 0..3
        int c4  = (tid & 31) << 2;                    // 0..124
        *reinterpret_cast<float4*>(&tile[row][c4]) =
            *reinterpret_cast<const float4*>(
                src + (size_t)(rowbase + row) * Dd + ds * 128 + c4);
    }
    __syncthreads();

    const float* wp = W1 + woff + (ds * 128) * Hh + tid;
    double a0 = 0.0, a1 = 0.0, a2 = 0.0, a3 = 0.0;
#pragma unroll 2
    for (int d4 = 0; d4 < 128; d4 += 4) {
        double w0 = (double)wp[(d4 + 0) * Hh];
        double w1 = (double)wp[(d4 + 1) * Hh];
        double w2 = (double)wp[(d4 + 2) * Hh];
        double w3 = (double)wp[(d4 + 3) * Hh];
        float4 t0 = *reinterpret_cast<const float4*>(&tile[0][d4]);
        float4 t1 = *reinterpret_cast<const float4*>(&tile[1][d4]);
        float4 t2 = *reinterpret_cast<const float4*>(&tile[2][d4]);
        float4 t3 = *reinterpret_cast<const float4*>(&tile[3][d4]);
        a0 = fma((double)t0.x, w0, a0); a0 = fma((double)t0.y, w1, a0);
        a0 = fma((double)t0.z, w2, a0); a0 = fma((double)t0.w, w3, a0);
        a1 = fma((double)t1.x, w0, a1); a1 = fma((double)t1.y, w1, a1);
        a1 = fma((double)t1.z, w2, a1); a1 = fma((double)t1.w, w3, a1);
        a2 = fma((double)t2.x, w0, a2); a2 = fma((double)t2.y, w1, a2);
        a2 = fma((double)t2.z, w2, a2); a2 = fma((double)t2.w, w3, a2);
        a3 = fma((double)t3.x, w0, a3); a3 = fma((double)t3.y, w1, a3);
        a3 = fma((double)t3.z, w2, a3); a3 = fma((double)t3.w, w3, a3);
    }
    int rowglob = (isQ ? 0 : Bb * Lq) + rowbase;      // 0..1535 (4-aligned)
    size_t obase = ((size_t)rowglob * 4 + ds) * Hh + tid;
    part[obase]            = a0;
    part[obase + 4 * Hh]   = a1;
    part[obase + 8 * Hh]   = a2;
    part[obase + 12 * Hh]  = a3;
}

// ---------------------------------------------------------------------------
// finalize: sum the 4 d-slice partials (deterministic order), add global
// dot; emit f64 hq_d/hk_d (for cleanup) and f32 hq/hk (+b1 on q) for main.
// 768 blocks x 256 threads, 2 rows per block.
__global__ __launch_bounds__(256) void finalize_kernel(
    const double* __restrict__ part,
    const double* __restrict__ gq_d, const double* __restrict__ gk_d,
    const float* __restrict__ b1,
    double* __restrict__ hq_d, double* __restrict__ hk_d,
    float* __restrict__ hq, float* __restrict__ hk)
{
    int tid = threadIdx.x;
    int bx  = blockIdx.x;
#pragma unroll
    for (int r = 0; r < 2; ++r) {
        int rowglob = bx * 2 + r;                     // 0..1535
        bool isQ = rowglob < Bb * Lq;
        int rr = isQ ? rowglob : rowglob - Bb * Lq;   // (b*Lq + row)
        int b  = rr / Lq;
        size_t pbase = ((size_t)rowglob * 4) * Hh + tid;
        double p0 = part[pbase];
        double p1 = part[pbase + 1 * Hh];
        double p2 = part[pbase + 2 * Hh];
        double p3 = part[pbase + 3 * Hh];
        double gl = (isQ ? gq_d : gk_d)[b * Hh + tid];
        double tot = ((p0 + p1) + (p2 + p3)) + gl;
        size_t o = (size_t)rr * Hh + tid;
        if (isQ) {
            hq_d[o] = tot;
            hq[o]   = (float)(tot + (double)b1[tid]);
        } else {
            hk_d[o] = tot;
            hk[o]   = (float)tot;
        }
    }
}

// ---------------------------------------------------------------------------
// sim: 32x32 tile, 2x2 per thread, float4 inner reads, K split in 2 halves.
__global__ __launch_bounds__(256) void sim_kernel(
    const float* __restrict__ q, const float* __restrict__ k,
    float* __restrict__ sim01)
{
    __shared__ __align__(16) float qs[32][132];
    __shared__ __align__(16) float ks[32][132];
    int tid = threadIdx.x;
    int bx = blockIdx.x;
    int kc = (bx >= Bb * 144) ? 1 : 0;
    int r  = bx - kc * Bb * 144;
    int b  = r / 144;  r %= 144;
    int lt = r / 12, st = r % 12;
    int tl = tid >> 4, ts = tid & 15;
    const float* qb = q + (b * Lq + lt * 32) * Dd;
    const float* kb = k + (b * Sk + st * 32) * Dd;
    float a00 = 0.f, a01 = 0.f, a10 = 0.f, a11 = 0.f;
    for (int c = kc * 256; c < kc * 256 + 256; c += 128) {
        __syncthreads();
        for (int i = tid; i < 1024; i += 256) {
            int row = i >> 5;
            int c4  = (i & 31) << 2;
            *reinterpret_cast<float4*>(&qs[row][c4]) =
                *reinterpret_cast<const float4*>(qb + row * Dd + c + c4);
            *reinterpret_cast<float4*>(&ks[row][c4]) =
                *reinterpret_cast<const float4*>(kb + row * Dd + c + c4);
        }
        __syncthreads();
#pragma unroll 2
        for (int dd = 0; dd < 128; dd += 4) {
            float4 q0 = *reinterpret_cast<const float4*>(&qs[tl][dd]);
            float4 q1 = *reinterpret_cast<const float4*>(&qs[tl + 16][dd]);
            float4 k0 = *reinterpret_cast<const float4*>(&ks[ts][dd]);
            float4 k1 = *reinterpret_cast<const float4*>(&ks[ts + 16][dd]);
            a00 = fmaf(q0.x, k0.x, a00); a00 = fmaf(q0.y, k0.y, a00);
            a00 = fmaf(q0.z, k0.z, a00); a00 = fmaf(q0.w, k0.w, a00);
            a01 = fmaf(q0.x, k1.x, a01); a01 = fmaf(q0.y, k1.y, a01);
            a01 = fmaf(q0.z, k1.z, a01); a01 = fmaf(q0.w, k1.w, a01);
            a10 = fmaf(q1.x, k0.x, a10); a10 = fmaf(q1.y, k0.y, a10);
            a10 = fmaf(q1.z, k0.z, a10); a10 = fmaf(q1.w, k0.w, a10);
            a11 = fmaf(q1.x, k1.x, a11); a11 = fmaf(q1.y, k1.y, a11);
            a11 = fmaf(q1.z, k1.z, a11); a11 = fmaf(q1.w, k1.w, a11);
        }
    }
    const float sc = 0.04419417382415922f;          // 1/sqrt(512)
    float* dst = sim01 + kc * (Bb * Lq * Sk);
    int l0 = lt * 32 + tl, s0 = st * 32 + ts;
    dst[(b * Lq + l0)      * Sk + s0]      = a00 * sc;
    dst[(b * Lq + l0)      * Sk + s0 + 16] = a01 * sc;
    dst[(b * Lq + l0 + 16) * Sk + s0]      = a10 * sc;
    dst[(b * Lq + l0 + 16) * Sk + s0 + 16] = a11 * sc;
}

// ---------------------------------------------------------------------------
// packed-pair gelu accumulate: y2 = 2*gelu(x); sums fold the 0.5 later.
__device__ __forceinline__ void gelu2(float2 hqv, float2 hkv, float2 gwv,
                                      float2& s1, float2& s2, float2& sw)
{
    const float P2   = 0.23164189f;            // 0.3275911/sqrt(2)
    const float A1f = 0.254829592f, A2f = -0.284496736f, A3f = 1.421413741f,
                A4f = -1.453152027f, A5f = 1.061405429f;
    const float NL2EH = -0.72134752044448170f; // -log2(e)/2

    float xa = hqv.x + hkv.x,        xb = hqv.y + hkv.y;
    float axa = fabsf(xa),           axb = fabsf(xb);
    float dda = fmaf(P2, axa, 1.0f), ddb = fmaf(P2, axb, 1.0f);
    float ta = __builtin_amdgcn_rcpf(dda), tb = __builtin_amdgcn_rcpf(ddb);
    float x2a = xa * xa,             x2b = xb * xb;
    float exa = __builtin_amdgcn_exp2f(x2a * NL2EH);
    float exb = __builtin_amdgcn_exp2f(x2b * NL2EH);
    float sa = fmaf(A5f, ta, A4f),   sb = fmaf(A5f, tb, A4f);
    sa = fmaf(sa, ta, A3f);          sb = fmaf(sb, tb, A3f);
    sa = fmaf(sa, ta, A2f);          sb = fmaf(sb, tb, A2f);
    sa = fmaf(sa, ta, A1f);          sb = fmaf(sb, tb, A1f);
    sa = sa * ta;                    sb = sb * tb;
    float Ea = fmaf(-sa, exa, 1.0f), Eb = fmaf(-sb, exb, 1.0f);
    float ya = fmaf(axa, Ea, xa),    yb = fmaf(axb, Eb, xb);   // = 2*gelu
    s1.x += ya;                      s1.y += yb;
    s2.x = fmaf(ya, ya, s2.x);       s2.y = fmaf(yb, yb, s2.y);
    sw.x = fmaf(ya, gwv.x, sw.x);    sw.y = fmaf(yb, gwv.y, sw.y);
}

// ---------------------------------------------------------------------------
// main: 32x16 (l,s) tile per 256-thread block; each thread 2 l-rows x 1 s.
__global__ __launch_bounds__(256) void main_kernel(
    const float* __restrict__ hq, const float* __restrict__ hk,
    const float* __restrict__ sim0, const float* __restrict__ sim1,
    const float* __restrict__ gam, const float* __restrict__ W2,
    const float* __restrict__ scal,
    const float* __restrict__ gu, float* __restrict__ out,
    int* __restrict__ cnt, int* __restrict__ list)
{
    __shared__ __align__(16) float hq_t[32][260];
    __shared__ __align__(16) float hk_t[16][260];
    __shared__ __align__(16) float gw_s[256];
    int tid = threadIdx.x;
    int bx = blockIdx.x;
    int b  = bx / (12 * 24);
    int r  = bx % (12 * 24);
    int lt = r / 24, st = r % 24;          // l-tile 32 rows, s-tile 16 cols

    const float* hqb = hq + (b * Lq + lt * 32) * Hh;
    const float* hkb = hk + (b * Sk + st * 16) * Hh;
#pragma unroll
    for (int i = 0; i < 8; ++i) {          // 32 rows x 64 float4
        int idx4 = i * 256 + tid;
        int row  = idx4 >> 6;
        int col4 = (idx4 & 63) << 2;
        *reinterpret_cast<float4*>(&hq_t[row][col4]) =
            *reinterpret_cast<const float4*>(hqb + row * Hh + col4);
    }
#pragma unroll
    for (int i = 0; i < 4; ++i) {          // 16 rows x 64 float4
        int idx4 = i * 256 + tid;
        int row  = idx4 >> 6;
        int col4 = (idx4 & 63) << 2;
        *reinterpret_cast<float4*>(&hk_t[row][col4]) =
            *reinterpret_cast<const float4*>(hkb + row * Hh + col4);
    }
    gw_s[tid] = gam[tid] * W2[tid];
    __syncthreads();
    float gwsum  = scal[0];
    float bconst = scal[1];

    int tl = tid >> 4, ts = tid & 15;
    float2 s1a = make_float2(0.f, 0.f), s2a = s1a, swa = s1a;
    float2 s1b = s1a, s2b = s1a, swb = s1a;
#pragma unroll 2
    for (int h4 = 0; h4 < Hh; h4 += 4) {
        float4 ha = *reinterpret_cast<const float4*>(&hq_t[tl][h4]);
        float4 hb = *reinterpret_cast<const float4*>(&hq_t[tl + 16][h4]);
        float4 kk = *reinterpret_cast<const float4*>(&hk_t[ts][h4]);
        float4 g4 = *reinterpret_cast<const float4*>(&gw_s[h4]);
        gelu2(make_float2(ha.x, ha.y), make_float2(kk.x, kk.y),
              make_float2(g4.x, g4.y), s1a, s2a, swa);
        gelu2(make_float2(ha.z, ha.w), make_float2(kk.z, kk.w),
              make_float2(g4.z, g4.w), s1a, s2a, swa);
        gelu2(make_float2(hb.x, hb.y), make_float2(kk.x, kk.y),
              make_float2(g4.x, g4.y), s1b, s2b, swb);
        gelu2(make_float2(hb.z, hb.w), make_float2(kk.z, kk.w),
              make_float2(g4.z, g4.w), s1b, s2b, swb);
    }

#pragma unroll
    for (int e = 0; e < 2; ++e) {
        float S1 = e ? (s1b.x + s1b.y) : (s1a.x + s1a.y);
        float S2 = e ? (s2b.x + s2b.y) : (s2a.x + s2a.y);
        float SW = 0.5f * (e ? (swb.x + swb.y) : (swa.x + swa.y));
        float mu   = S1 * (1.0f / 512.0f);
        float var  = S2 * (1.0f / 1024.0f) - mu * mu;
        float rstd = rsqrtf(var + 1e-5f);
        float thr  = rstd * (SW - mu * gwsum) + bconst;

        int l = lt * 32 + tl + e * 16, s = st * 16 + ts;
        int idx = (b * Lq + l) * Sk + s;
        float  sv = sim0[idx] + sim1[idx];
        float2 uv = reinterpret_cast<const float2*>(gu)[idx];
        float u0 = fminf(fmaxf(uv.x, 1e-6f), 1.0f - 1e-6f);
        float u1 = fminf(fmaxf(uv.y, 1e-6f), 1.0f - 1e-6f);
        float g0 = -logf(-logf(u0));
        float g1 = -logf(-logf(u1));
        float t  = 0.2f * (sv - thr) + (g1 - g0);
        out[idx] = t > 0.0f ? 1.0f : 0.0f;
        if (fabsf(t) < 1e-3f) {
            int p = atomicAdd(cnt, 1);
            if (p < LIST_CAP) list[p] = idx;
        }
    }
}

// ---------------------------------------------------------------------------
// cleanup: per flagged item, f64 finish using precomputed f64 projections.
__global__ __launch_bounds__(256) void cleanup_kernel(
    const float* __restrict__ q, const float* __restrict__ k,
    const double* __restrict__ hq_d, const double* __restrict__ hk_d,
    const float* __restrict__ b1,
    const float* __restrict__ gam, const float* __restrict__ bet,
    const float* __restrict__ W2, const float* __restrict__ b2,
    const float* __restrict__ gu, float* __restrict__ out,
    const int* __restrict__ cnt, const int* __restrict__ list)
{
    __shared__ double s0[256], s1[256], s2[256], s3[256];
    int tid = threadIdx.x;
    int n = *cnt;
    if (n > LIST_CAP) n = LIST_CAP;
    if (n == 0) return;

    double gw  = (double)gam[tid] * (double)W2[tid];
    double b1d = (double)b1[tid];
    s0[tid] = (double)bet[tid] * (double)W2[tid];
    s1[tid] = gw;
    __syncthreads();
    for (int o = 128; o > 0; o >>= 1) {
        if (tid < o) { s0[tid] += s0[tid + o]; s1[tid] += s1[tid + o]; }
        __syncthreads();
    }
    double bconst = s0[0] + (double)b2[0];
    double gwsum  = s1[0];
    __syncthreads();

    for (int it = blockIdx.x; it < n; it += gridDim.x) {
        int idx = list[it];
        int b   = idx / (Lq * Sk);
        int rem = idx % (Lq * Sk);
        int l = rem / Sk, s = rem % Sk;
        double x = (hq_d[(b * Lq + l) * Hh + tid]
                  + hk_d[(b * Sk + s) * Hh + tid]) + b1d;
        double y = 0.5 * x * (1.0 + erf(x * 0.70710678118654752440));
        const float* qrow = q + (b * Lq + l) * Dd;
        const float* krow = k + (b * Sk + s) * Dd;
        double sp = (double)qrow[tid] * (double)krow[tid]
                  + (double)qrow[tid + 256] * (double)krow[tid + 256];
        s0[tid] = y; s1[tid] = y * y; s2[tid] = y * gw; s3[tid] = sp;
        __syncthreads();
        for (int o = 128; o > 0; o >>= 1) {
            if (tid < o) {
                s0[tid] += s0[tid + o]; s1[tid] += s1[tid + o];
                s2[tid] += s2[tid + o]; s3[tid] += s3[tid + o];
            }
            __syncthreads();
        }
        if (tid == 0) {
            double mu   = s0[0] * (1.0 / 256.0);
            double var  = s1[0] * (1.0 / 256.0) - mu * mu;
            double rstd = 1.0 / sqrt(var + 1e-5);
            double thr  = rstd * (s2[0] - mu * gwsum) + bconst;
            double simv = s3[0] / 22.627416997969522;   // sqrt(512)
            float2 uv = reinterpret_cast<const float2*>(gu)[idx];
            double u0 = fmin(fmax((double)uv.x, 1e-6), 1.0 - 1e-6);
            double u1 = fmin(fmax((double)uv.y, 1e-6), 1.0 - 1e-6);
            double g0 = -log(-log(u0));
            double g1 = -log(-log(u1));
            double t  = 0.2 * (simv - thr) + (g1 - g0);
            out[idx] = t > 0.0 ? 1.0f : 0.0f;
        }
        __syncthreads();
    }
}

// ---------------------------------------------------------------------------
extern "C" void kernel_launch(void* const* d_in, const int* in_sizes, int n_in,
                              void* d_out, int out_size, void* d_ws, size_t ws_size,
                              hipStream_t stream)
{
    const float* q   = (const float*)d_in[0];
    const float* k   = (const float*)d_in[1];
    const float* qg  = (const float*)d_in[2];
    const float* kg  = (const float*)d_in[3];
    const float* W1  = (const float*)d_in[4];
    const float* b1  = (const float*)d_in[5];
    const float* gam = (const float*)d_in[6];
    const float* bet = (const float*)d_in[7];
    const float* W2  = (const float*)d_in[8];
    const float* b2  = (const float*)d_in[9];
    const float* gu  = (const float*)d_in[10];
    float* out = (float*)d_out;

    char*   ws   = (char*)d_ws;
    double* hq_d = (double*)(ws + HQD_OFF);
    double* hk_d = (double*)(ws + HKD_OFF);
    double* part = (double*)(ws + PART_OFF);
    double* gq_d = (double*)(ws + GQD_OFF);
    double* gk_d = (double*)(ws + GKD_OFF);
    float*  hq   = (float*)(ws + HQ_OFF);
    float*  hk   = (float*)(ws + HK_OFF);
    float*  sim0 = (float*)(ws + SIM0_OFF);
    float*  sim1 = (float*)(ws + SIM1_OFF);
    float*  scal = (float*)(ws + SCAL_OFF);
    int*    cnt  = (int*)(ws + CNT_OFF);
    int*    list = (int*)(ws + LIST_OFF);

    smalls_kernel<<<17, 256, 0, stream>>>(
        qg, kg, W1, gam, bet, W2, b2, gq_d, gk_d, scal, cnt);
    projd_part_kernel<<<NROWS, 256, 0, stream>>>(q, k, W1, part);
    finalize_kernel<<<NROWS / 2, 256, 0, stream>>>(
        part, gq_d, gk_d, b1, hq_d, hk_d, hq, hk);
    sim_kernel<<<2 * Bb * 144, 256, 0, stream>>>(q, k, sim0);
    main_kernel<<<Bb * 12 * 24, 256, 0, stream>>>(
        hq, hk, sim0, sim1, gam, W2, scal, gu, out, cnt, list);
    cleanup_kernel<<<768, 256, 0, stream>>>(
        q, k, hq_d, hk_d, b1, gam, bet, W2, b2, gu, out, cnt, list);
}

// Round 11
// 157.250 us; speedup vs baseline: 1.1133x; 1.0882x over previous
//
#include <hip/hip_runtime.h>
#include <hip/hip_bf16.h>
#include <math.h>

#define Bb 2
#define Lq 384
#define Sk 384
#define Dd 512
#define Hh 256

#define LIST_CAP 65536
#define NROWS (2 * Bb * Lq)          // 1536 total rows (q then k)

// workspace layout (bytes) — f64 regions first for 8B alignment
#define HQD_OFF  0                                   // B*L*H doubles
#define HKD_OFF  (HQD_OFF + Bb*Lq*Hh*8)              // B*S*H doubles
#define PART_OFF (HKD_OFF + Bb*Sk*Hh*8)              // 1536*4*256 doubles
#define GQD_OFF  (PART_OFF + NROWS*4*Hh*8)
#define GKD_OFF  (GQD_OFF + Bb*Hh*8)
#define HQ_OFF   (GKD_OFF + Bb*Hh*8)                 // B*L*H floats
#define HK_OFF   (HQ_OFF + Bb*Lq*Hh*4)               // B*S*H floats
#define SIM0_OFF (HK_OFF + Bb*Sk*Hh*4)               // B*L*S floats
#define SIM1_OFF (SIM0_OFF + Bb*Lq*Sk*4)             // B*L*S floats
#define SCAL_OFF (SIM1_OFF + Bb*Lq*Sk*4)             // 2 floats
#define CNT_OFF  (SCAL_OFF + 64)                     // 1 int
#define LIST_OFF (CNT_OFF + 64)                      // LIST_CAP ints

// ---------------------------------------------------------------------------
// fused proj: bx<17 = "smalls" prologue blocks (f64 global-vector dots,
// scal={gwsum,bconst}, cnt=0); bx>=17 = projd_part (f64 row-projection
// partials: 4 rows x 128-d slice x 256 h-threads, grid 1536).
__global__ __launch_bounds__(256) void proj_fused_kernel(
    const float* __restrict__ q, const float* __restrict__ k,
    const float* __restrict__ qg, const float* __restrict__ kg,
    const float* __restrict__ W1,
    const float* __restrict__ gam, const float* __restrict__ bet,
    const float* __restrict__ W2, const float* __restrict__ b2,
    double* __restrict__ gq_d, double* __restrict__ gk_d,
    float* __restrict__ scal, int* __restrict__ cnt,
    double* __restrict__ part)
{
    __shared__ double red[64][5];
    __shared__ float2 red2[256];
    __shared__ __align__(16) float tile[4][128];
    int bx  = blockIdx.x;
    int tid = threadIdx.x;
    if (bx < 16) {
        int isK = bx & 1;
        int b   = (bx >> 1) & 1;
        int hc  = bx >> 2;                  // 0..3
        int hl  = tid >> 2;                 // 0..63
        int dp  = tid & 3;                  // 0..3
        int h   = hc * 64 + hl;
        const float* gv = (isK ? kg : qg) + b * Dd;
        const float* wp = W1 + (isK ? 3 : 2) * Dd * Hh + h;
        int d0 = dp * 128;
        double a0 = 0, a1 = 0, a2 = 0, a3 = 0;
        for (int i = 0; i < 128; i += 4) {
            int d = d0 + i;
            a0 = fma((double)gv[d + 0], (double)wp[(d + 0) * Hh], a0);
            a1 = fma((double)gv[d + 1], (double)wp[(d + 1) * Hh], a1);
            a2 = fma((double)gv[d + 2], (double)wp[(d + 2) * Hh], a2);
            a3 = fma((double)gv[d + 3], (double)wp[(d + 3) * Hh], a3);
        }
        red[hl][dp] = ((a0 + a1) + (a2 + a3));
        __syncthreads();
        if (dp == 0) {
            double s = (red[hl][0] + red[hl][1]) + (red[hl][2] + red[hl][3]);
            (isK ? gk_d : gq_d)[b * Hh + h] = s;
        }
    } else if (bx == 16) {
        if (tid == 0) *cnt = 0;
        float w2v = W2[tid];
        red2[tid] = make_float2(gam[tid] * w2v, bet[tid] * w2v);
        __syncthreads();
        for (int o = 128; o > 0; o >>= 1) {
            if (tid < o) {
                red2[tid].x += red2[tid + o].x;
                red2[tid].y += red2[tid + o].y;
            }
            __syncthreads();
        }
        if (tid == 0) {
            scal[0] = red2[0].x;
            scal[1] = red2[0].y + b2[0];
        }
    } else {
        int bxp = bx - 17;                            // 0..1535
        int ds  = bxp & 3;                            // d-slice 0..3
        int rgid = bxp >> 2;                          // 0..383
        bool isQ = rgid < 192;
        int bb = isQ ? rgid : rgid - 192;
        int b  = bb / 96;
        int rg = bb % 96;                             // 4-row group
        const float* src = isQ ? q : k;
        int woff = isQ ? 0 : Dd * Hh;
        int rowbase = b * Lq + rg * 4;

        if (tid < 128) {
            int row = tid >> 5;
            int c4  = (tid & 31) << 2;
            *reinterpret_cast<float4*>(&tile[row][c4]) =
                *reinterpret_cast<const float4*>(
                    src + (size_t)(rowbase + row) * Dd + ds * 128 + c4);
        }
        __syncthreads();

        const float* wp = W1 + woff + (ds * 128) * Hh + tid;
        double a0 = 0.0, a1 = 0.0, a2 = 0.0, a3 = 0.0;
#pragma unroll 2
        for (int d4 = 0; d4 < 128; d4 += 4) {
            double w0 = (double)wp[(d4 + 0) * Hh];
            double w1 = (double)wp[(d4 + 1) * Hh];
            double w2 = (double)wp[(d4 + 2) * Hh];
            double w3 = (double)wp[(d4 + 3) * Hh];
            float4 t0 = *reinterpret_cast<const float4*>(&tile[0][d4]);
            float4 t1 = *reinterpret_cast<const float4*>(&tile[1][d4]);
            float4 t2 = *reinterpret_cast<const float4*>(&tile[2][d4]);
            float4 t3 = *reinterpret_cast<const float4*>(&tile[3][d4]);
            a0 = fma((double)t0.x, w0, a0); a0 = fma((double)t0.y, w1, a0);
            a0 = fma((double)t0.z, w2, a0); a0 = fma((double)t0.w, w3, a0);
            a1 = fma((double)t1.x, w0, a1); a1 = fma((double)t1.y, w1, a1);
            a1 = fma((double)t1.z, w2, a1); a1 = fma((double)t1.w, w3, a1);
            a2 = fma((double)t2.x, w0, a2); a2 = fma((double)t2.y, w1, a2);
            a2 = fma((double)t2.z, w2, a2); a2 = fma((double)t2.w, w3, a2);
            a3 = fma((double)t3.x, w0, a3); a3 = fma((double)t3.y, w1, a3);
            a3 = fma((double)t3.z, w2, a3); a3 = fma((double)t3.w, w3, a3);
        }
        int rowglob = (isQ ? 0 : Bb * Lq) + rowbase;
        size_t obase = ((size_t)rowglob * 4 + ds) * Hh + tid;
        part[obase]           = a0;
        part[obase + 4 * Hh]  = a1;
        part[obase + 8 * Hh]  = a2;
        part[obase + 12 * Hh] = a3;
    }
}

// ---------------------------------------------------------------------------
// finalize: sum the 4 d-slice partials (deterministic), add global dot;
// emit f64 hq_d/hk_d (cleanup) and f32 hq/hk (+b1 on q) for main.
__global__ __launch_bounds__(256) void finalize_kernel(
    const double* __restrict__ part,
    const double* __restrict__ gq_d, const double* __restrict__ gk_d,
    const float* __restrict__ b1,
    double* __restrict__ hq_d, double* __restrict__ hk_d,
    float* __restrict__ hq, float* __restrict__ hk)
{
    int tid = threadIdx.x;
    int bx  = blockIdx.x;
#pragma unroll
    for (int r = 0; r < 2; ++r) {
        int rowglob = bx * 2 + r;                     // 0..1535
        bool isQ = rowglob < Bb * Lq;
        int rr = isQ ? rowglob : rowglob - Bb * Lq;
        int b  = rr / Lq;
        size_t pbase = ((size_t)rowglob * 4) * Hh + tid;
        double p0 = part[pbase];
        double p1 = part[pbase + 1 * Hh];
        double p2 = part[pbase + 2 * Hh];
        double p3 = part[pbase + 3 * Hh];
        double gl = (isQ ? gq_d : gk_d)[b * Hh + tid];
        double tot = ((p0 + p1) + (p2 + p3)) + gl;
        size_t o = (size_t)rr * Hh + tid;
        if (isQ) {
            hq_d[o] = tot;
            hq[o]   = (float)(tot + (double)b1[tid]);
        } else {
            hk_d[o] = tot;
            hk[o]   = (float)tot;
        }
    }
}

// ---------------------------------------------------------------------------
// sim: 32x32 tile, 2x2 per thread, float4 inner reads, K split in 2 halves.
__global__ __launch_bounds__(256) void sim_kernel(
    const float* __restrict__ q, const float* __restrict__ k,
    float* __restrict__ sim01)
{
    __shared__ __align__(16) float qs[32][132];
    __shared__ __align__(16) float ks[32][132];
    int tid = threadIdx.x;
    int bx = blockIdx.x;
    int kc = (bx >= Bb * 144) ? 1 : 0;
    int r  = bx - kc * Bb * 144;
    int b  = r / 144;  r %= 144;
    int lt = r / 12, st = r % 12;
    int tl = tid >> 4, ts = tid & 15;
    const float* qb = q + (b * Lq + lt * 32) * Dd;
    const float* kb = k + (b * Sk + st * 32) * Dd;
    float a00 = 0.f, a01 = 0.f, a10 = 0.f, a11 = 0.f;
    for (int c = kc * 256; c < kc * 256 + 256; c += 128) {
        __syncthreads();
        for (int i = tid; i < 1024; i += 256) {
            int row = i >> 5;
            int c4  = (i & 31) << 2;
            *reinterpret_cast<float4*>(&qs[row][c4]) =
                *reinterpret_cast<const float4*>(qb + row * Dd + c + c4);
            *reinterpret_cast<float4*>(&ks[row][c4]) =
                *reinterpret_cast<const float4*>(kb + row * Dd + c + c4);
        }
        __syncthreads();
#pragma unroll 2
        for (int dd = 0; dd < 128; dd += 4) {
            float4 q0 = *reinterpret_cast<const float4*>(&qs[tl][dd]);
            float4 q1 = *reinterpret_cast<const float4*>(&qs[tl + 16][dd]);
            float4 k0 = *reinterpret_cast<const float4*>(&ks[ts][dd]);
            float4 k1 = *reinterpret_cast<const float4*>(&ks[ts + 16][dd]);
            a00 = fmaf(q0.x, k0.x, a00); a00 = fmaf(q0.y, k0.y, a00);
            a00 = fmaf(q0.z, k0.z, a00); a00 = fmaf(q0.w, k0.w, a00);
            a01 = fmaf(q0.x, k1.x, a01); a01 = fmaf(q0.y, k1.y, a01);
            a01 = fmaf(q0.z, k1.z, a01); a01 = fmaf(q0.w, k1.w, a01);
            a10 = fmaf(q1.x, k0.x, a10); a10 = fmaf(q1.y, k0.y, a10);
            a10 = fmaf(q1.z, k0.z, a10); a10 = fmaf(q1.w, k0.w, a10);
            a11 = fmaf(q1.x, k1.x, a11); a11 = fmaf(q1.y, k1.y, a11);
            a11 = fmaf(q1.z, k1.z, a11); a11 = fmaf(q1.w, k1.w, a11);
        }
    }
    const float sc = 0.04419417382415922f;          // 1/sqrt(512)
    float* dst = sim01 + kc * (Bb * Lq * Sk);
    int l0 = lt * 32 + tl, s0 = st * 32 + ts;
    dst[(b * Lq + l0)      * Sk + s0]      = a00 * sc;
    dst[(b * Lq + l0)      * Sk + s0 + 16] = a01 * sc;
    dst[(b * Lq + l0 + 16) * Sk + s0]      = a10 * sc;
    dst[(b * Lq + l0 + 16) * Sk + s0 + 16] = a11 * sc;
}

// ---------------------------------------------------------------------------
// tanh-gelu pair accumulate: y2 = 2*gelu_tanh(x) = 2x*sigmoid(x*(K1+K2*x^2)).
// 7 VALU + 2 trans per element (vs 11+2 for A&S erf). |y2 - 2*gelu_exact|
// <= ~8e-4; t-error ~2e-4 RMS, covered by the 2e-3 flag margin.
__device__ __forceinline__ void gelu2t(float2 hqv, float2 hkv, float2 gwv,
                                       float2& s1, float2& s2, float2& sw)
{
    const float K1 = -2.30220815f;    // -2*log2(e)*sqrt(2/pi)
    const float K2 = -0.10294325f;    // K1 * 0.044715
    float xa = hqv.x + hkv.x,  xb = hqv.y + hkv.y;
    float x2a = xa * xa,       x2b = xb * xb;
    float pa = fmaf(K2, x2a, K1), pb = fmaf(K2, x2b, K1);
    float za = xa * pa,        zb = xb * pb;
    float ea = __builtin_amdgcn_exp2f(za);
    float eb = __builtin_amdgcn_exp2f(zb);
    float ra = __builtin_amdgcn_rcpf(1.0f + ea);
    float rb = __builtin_amdgcn_rcpf(1.0f + eb);
    float ya = (xa + xa) * ra, yb = (xb + xb) * rb;  // = 2*gelu
    s1.x += ya;                s1.y += yb;
    s2.x = fmaf(ya, ya, s2.x); s2.y = fmaf(yb, yb, s2.y);
    sw.x = fmaf(ya, gwv.x, sw.x); sw.y = fmaf(yb, gwv.y, sw.y);
}

// ---------------------------------------------------------------------------
// main: 32x16 (l,s) tile per 512-thread block. Lane pair (2t,2t+1) shares
// one (2-row x 1-col) output set, split over h-halves (h-split doubles
// resident waves: 4.5/SIMD vs 2.25 before). Combine via __shfl_xor(.,1);
// lane hh=0 finishes row tl, hh=1 row tl+16.
__global__ __launch_bounds__(512) void main_kernel(
    const float* __restrict__ hq, const float* __restrict__ hk,
    const float* __restrict__ sim0, const float* __restrict__ sim1,
    const float* __restrict__ gam, const float* __restrict__ W2,
    const float* __restrict__ scal,
    const float* __restrict__ gu, float* __restrict__ out,
    int* __restrict__ cnt, int* __restrict__ list)
{
    __shared__ __align__(16) float hq_t[32][260];
    __shared__ __align__(16) float hk_t[16][260];
    __shared__ __align__(16) float gw_s[256];
    int tid = threadIdx.x;
    int bx = blockIdx.x;
    int b  = bx / (12 * 24);
    int r  = bx % (12 * 24);
    int lt = r / 24, st = r % 24;          // l-tile 32 rows, s-tile 16 cols

    const float* hqb = hq + (b * Lq + lt * 32) * Hh;
    const float* hkb = hk + (b * Sk + st * 16) * Hh;
#pragma unroll
    for (int i = 0; i < 4; ++i) {          // 32 rows x 64 float4 = 2048
        int idx4 = i * 512 + tid;
        int row  = idx4 >> 6;
        int col4 = (idx4 & 63) << 2;
        *reinterpret_cast<float4*>(&hq_t[row][col4]) =
            *reinterpret_cast<const float4*>(hqb + row * Hh + col4);
    }
#pragma unroll
    for (int i = 0; i < 2; ++i) {          // 16 rows x 64 float4 = 1024
        int idx4 = i * 512 + tid;
        int row  = idx4 >> 6;
        int col4 = (idx4 & 63) << 2;
        *reinterpret_cast<float4*>(&hk_t[row][col4]) =
            *reinterpret_cast<const float4*>(hkb + row * Hh + col4);
    }
    if (tid < 256) gw_s[tid] = gam[tid] * W2[tid];
    __syncthreads();
    float gwsum  = scal[0];
    float bconst = scal[1];

    int opair = tid >> 1;                  // 0..255: output-pair id
    int hh    = tid & 1;                   // h-half
    int tl = opair >> 4, ts = opair & 15;

    float2 s1a = make_float2(0.f, 0.f), s2a = s1a, swa = s1a;
    float2 s1b = s1a, s2b = s1a, swb = s1a;
    int h0 = hh << 7;                      // 0 or 128
#pragma unroll 2
    for (int h4 = h0; h4 < h0 + 128; h4 += 4) {
        float4 ha = *reinterpret_cast<const float4*>(&hq_t[tl][h4]);
        float4 hb = *reinterpret_cast<const float4*>(&hq_t[tl + 16][h4]);
        float4 kk = *reinterpret_cast<const float4*>(&hk_t[ts][h4]);
        float4 g4 = *reinterpret_cast<const float4*>(&gw_s[h4]);
        gelu2t(make_float2(ha.x, ha.y), make_float2(kk.x, kk.y),
               make_float2(g4.x, g4.y), s1a, s2a, swa);
        gelu2t(make_float2(ha.z, ha.w), make_float2(kk.z, kk.w),
               make_float2(g4.z, g4.w), s1a, s2a, swa);
        gelu2t(make_float2(hb.x, hb.y), make_float2(kk.x, kk.y),
               make_float2(g4.x, g4.y), s1b, s2b, swb);
        gelu2t(make_float2(hb.z, hb.w), make_float2(kk.z, kk.w),
               make_float2(g4.z, g4.w), s1b, s2b, swb);
    }
    // per-lane pair-collapse, then cross-lane combine (lanes 2t <-> 2t+1)
    float S1a = s1a.x + s1a.y;  S1a += __shfl_xor(S1a, 1, 64);
    float S2a = s2a.x + s2a.y;  S2a += __shfl_xor(S2a, 1, 64);
    float SWa = swa.x + swa.y;  SWa += __shfl_xor(SWa, 1, 64);
    float S1b = s1b.x + s1b.y;  S1b += __shfl_xor(S1b, 1, 64);
    float S2b = s2b.x + s2b.y;  S2b += __shfl_xor(S2b, 1, 64);
    float SWb = swb.x + swb.y;  SWb += __shfl_xor(SWb, 1, 64);

    float S1 = hh ? S1b : S1a;             // lane hh handles its row
    float S2 = hh ? S2b : S2a;
    float SW = 0.5f * (hh ? SWb : SWa);
    float mu   = S1 * (1.0f / 512.0f);
    float var  = S2 * (1.0f / 1024.0f) - mu * mu;
    float rstd = rsqrtf(var + 1e-5f);
    float thr  = rstd * (SW - mu * gwsum) + bconst;

    int l = lt * 32 + tl + hh * 16, s = st * 16 + ts;
    int idx = (b * Lq + l) * Sk + s;
    float  sv = sim0[idx] + sim1[idx];
    float2 uv = reinterpret_cast<const float2*>(gu)[idx];
    float u0 = fminf(fmaxf(uv.x, 1e-6f), 1.0f - 1e-6f);
    float u1 = fminf(fmaxf(uv.y, 1e-6f), 1.0f - 1e-6f);
    float g0 = -logf(-logf(u0));
    float g1 = -logf(-logf(u1));
    float t  = 0.2f * (sv - thr) + (g1 - g0);
    out[idx] = t > 0.0f ? 1.0f : 0.0f;
    if (fabsf(t) < 2e-3f) {
        int p = atomicAdd(cnt, 1);
        if (p < LIST_CAP) list[p] = idx;
    }
}

// ---------------------------------------------------------------------------
// cleanup: per flagged item, exact-f64 finish using precomputed projections.
__global__ __launch_bounds__(256) void cleanup_kernel(
    const float* __restrict__ q, const float* __restrict__ k,
    const double* __restrict__ hq_d, const double* __restrict__ hk_d,
    const float* __restrict__ b1,
    const float* __restrict__ gam, const float* __restrict__ bet,
    const float* __restrict__ W2, const float* __restrict__ b2,
    const float* __restrict__ gu, float* __restrict__ out,
    const int* __restrict__ cnt, const int* __restrict__ list)
{
    __shared__ double s0[256], s1[256], s2[256], s3[256];
    int tid = threadIdx.x;
    int n = *cnt;
    if (n > LIST_CAP) n = LIST_CAP;
    if (n == 0) return;

    double gw  = (double)gam[tid] * (double)W2[tid];
    double b1d = (double)b1[tid];
    s0[tid] = (double)bet[tid] * (double)W2[tid];
    s1[tid] = gw;
    __syncthreads();
    for (int o = 128; o > 0; o >>= 1) {
        if (tid < o) { s0[tid] += s0[tid + o]; s1[tid] += s1[tid + o]; }
        __syncthreads();
    }
    double bconst = s0[0] + (double)b2[0];
    double gwsum  = s1[0];
    __syncthreads();

    for (int it = blockIdx.x; it < n; it += gridDim.x) {
        int idx = list[it];
        int b   = idx / (Lq * Sk);
        int rem = idx % (Lq * Sk);
        int l = rem / Sk, s = rem % Sk;
        double x = (hq_d[(b * Lq + l) * Hh + tid]
                  + hk_d[(b * Sk + s) * Hh + tid]) + b1d;
        double y = 0.5 * x * (1.0 + erf(x * 0.70710678118654752440));
        const float* qrow = q + (b * Lq + l) * Dd;
        const float* krow = k + (b * Sk + s) * Dd;
        double sp = (double)qrow[tid] * (double)krow[tid]
                  + (double)qrow[tid + 256] * (double)krow[tid + 256];
        s0[tid] = y; s1[tid] = y * y; s2[tid] = y * gw; s3[tid] = sp;
        __syncthreads();
        for (int o = 128; o > 0; o >>= 1) {
            if (tid < o) {
                s0[tid] += s0[tid + o]; s1[tid] += s1[tid + o];
                s2[tid] += s2[tid + o]; s3[tid] += s3[tid + o];
            }
            __syncthreads();
        }
        if (tid == 0) {
            double mu   = s0[0] * (1.0 / 256.0);
            double var  = s1[0] * (1.0 / 256.0) - mu * mu;
            double rstd = 1.0 / sqrt(var + 1e-5);
            double thr  = rstd * (s2[0] - mu * gwsum) + bconst;
            double simv = s3[0] / 22.627416997969522;   // sqrt(512)
            float2 uv = reinterpret_cast<const float2*>(gu)[idx];
            double u0 = fmin(fmax((double)uv.x, 1e-6), 1.0 - 1e-6);
            double u1 = fmin(fmax((double)uv.y, 1e-6), 1.0 - 1e-6);
            double g0 = -log(-log(u0));
            double g1 = -log(-log(u1));
            double t  = 0.2 * (simv - thr) + (g1 - g0);
            out[idx] = t > 0.0 ? 1.0f : 0.0f;
        }
        __syncthreads();
    }
}

// ---------------------------------------------------------------------------
extern "C" void kernel_launch(void* const* d_in, const int* in_sizes, int n_in,
                              void* d_out, int out_size, void* d_ws, size_t ws_size,
                              hipStream_t stream)
{
    const float* q   = (const float*)d_in[0];
    const float* k   = (const float*)d_in[1];
    const float* qg  = (const float*)d_in[2];
    const float* kg  = (const float*)d_in[3];
    const float* W1  = (const float*)d_in[4];
    const float* b1  = (const float*)d_in[5];
    const float* gam = (const float*)d_in[6];
    const float* bet = (const float*)d_in[7];
    const float* W2  = (const float*)d_in[8];
    const float* b2  = (const float*)d_in[9];
    const float* gu  = (const float*)d_in[10];
    float* out = (float*)d_out;

    char*   ws   = (char*)d_ws;
    double* hq_d = (double*)(ws + HQD_OFF);
    double* hk_d = (double*)(ws + HKD_OFF);
    double* part = (double*)(ws + PART_OFF);
    double* gq_d = (double*)(ws + GQD_OFF);
    double* gk_d = (double*)(ws + GKD_OFF);
    float*  hq   = (float*)(ws + HQ_OFF);
    float*  hk   = (float*)(ws + HK_OFF);
    float*  sim0 = (float*)(ws + SIM0_OFF);
    float*  sim1 = (float*)(ws + SIM1_OFF);
    float*  scal = (float*)(ws + SCAL_OFF);
    int*    cnt  = (int*)(ws + CNT_OFF);
    int*    list = (int*)(ws + LIST_OFF);

    proj_fused_kernel<<<17 + NROWS, 256, 0, stream>>>(
        q, k, qg, kg, W1, gam, bet, W2, b2, gq_d, gk_d, scal, cnt, part);
    finalize_kernel<<<NROWS / 2, 256, 0, stream>>>(
        part, gq_d, gk_d, b1, hq_d, hk_d, hq, hk);
    sim_kernel<<<2 * Bb * 144, 256, 0, stream>>>(q, k, sim0);
    main_kernel<<<Bb * 12 * 24, 512, 0, stream>>>(
        hq, hk, sim0, sim1, gam, W2, scal, gu, out, cnt, list);
    cleanup_kernel<<<768, 256, 0, stream>>>(
        q, k, hq_d, hk_d, b1, gam, bet, W2, b2, gu, out, cnt, list);
}

// Round 12
// 157.199 us; speedup vs baseline: 1.1137x; 1.0003x over previous
//
#include <hip/hip_runtime.h>
#include <hip/hip_bf16.h>
#include <math.h>

#define Bb 2
#define Lq 384
#define Sk 384
#define Dd 512
#define Hh 256

#define LIST_CAP 65536
#define NROWS (2 * Bb * Lq)          // 1536 total rows (q then k)
#define PLANE (Bb * Lq * Sk)         // elements per sim partial plane

// workspace layout (bytes) — f64 regions first for 8B alignment
#define HQD_OFF  0                                   // B*L*H doubles
#define HKD_OFF  (HQD_OFF + Bb*Lq*Hh*8)              // B*S*H doubles
#define PART_OFF (HKD_OFF + Bb*Sk*Hh*8)              // 1536*4*256 doubles
#define GQD_OFF  (PART_OFF + NROWS*4*Hh*8)
#define GKD_OFF  (GQD_OFF + Bb*Hh*8)
#define HQ_OFF   (GKD_OFF + Bb*Hh*8)                 // B*L*H floats
#define HK_OFF   (HQ_OFF + Bb*Lq*Hh*4)               // B*S*H floats
#define SIM_OFF  (HK_OFF + Bb*Sk*Hh*4)               // 8 planes x B*L*S floats
#define SCAL_OFF (SIM_OFF + 8*PLANE*4)               // 2 floats
#define CNT_OFF  (SCAL_OFF + 64)                     // 1 int
#define LIST_OFF (CNT_OFF + 64)                      // LIST_CAP ints

// ---------------------------------------------------------------------------
// fused proj: bx<17 = "smalls" prologue blocks (f64 global-vector dots,
// scal={gwsum,bconst}, cnt=0); bx>=17 = projd_part (f64 row-projection
// partials: 4 rows x 128-d slice x 256 h-threads, grid 1536).
__global__ __launch_bounds__(256) void proj_fused_kernel(
    const float* __restrict__ q, const float* __restrict__ k,
    const float* __restrict__ qg, const float* __restrict__ kg,
    const float* __restrict__ W1,
    const float* __restrict__ gam, const float* __restrict__ bet,
    const float* __restrict__ W2, const float* __restrict__ b2,
    double* __restrict__ gq_d, double* __restrict__ gk_d,
    float* __restrict__ scal, int* __restrict__ cnt,
    double* __restrict__ part)
{
    __shared__ double red[64][5];
    __shared__ float2 red2[256];
    __shared__ __align__(16) float tile[4][128];
    int bx  = blockIdx.x;
    int tid = threadIdx.x;
    if (bx < 16) {
        int isK = bx & 1;
        int b   = (bx >> 1) & 1;
        int hc  = bx >> 2;                  // 0..3
        int hl  = tid >> 2;                 // 0..63
        int dp  = tid & 3;                  // 0..3
        int h   = hc * 64 + hl;
        const float* gv = (isK ? kg : qg) + b * Dd;
        const float* wp = W1 + (isK ? 3 : 2) * Dd * Hh + h;
        int d0 = dp * 128;
        double a0 = 0, a1 = 0, a2 = 0, a3 = 0;
        for (int i = 0; i < 128; i += 4) {
            int d = d0 + i;
            a0 = fma((double)gv[d + 0], (double)wp[(d + 0) * Hh], a0);
            a1 = fma((double)gv[d + 1], (double)wp[(d + 1) * Hh], a1);
            a2 = fma((double)gv[d + 2], (double)wp[(d + 2) * Hh], a2);
            a3 = fma((double)gv[d + 3], (double)wp[(d + 3) * Hh], a3);
        }
        red[hl][dp] = ((a0 + a1) + (a2 + a3));
        __syncthreads();
        if (dp == 0) {
            double s = (red[hl][0] + red[hl][1]) + (red[hl][2] + red[hl][3]);
            (isK ? gk_d : gq_d)[b * Hh + h] = s;
        }
    } else if (bx == 16) {
        if (tid == 0) *cnt = 0;
        float w2v = W2[tid];
        red2[tid] = make_float2(gam[tid] * w2v, bet[tid] * w2v);
        __syncthreads();
        for (int o = 128; o > 0; o >>= 1) {
            if (tid < o) {
                red2[tid].x += red2[tid + o].x;
                red2[tid].y += red2[tid + o].y;
            }
            __syncthreads();
        }
        if (tid == 0) {
            scal[0] = red2[0].x;
            scal[1] = red2[0].y + b2[0];
        }
    } else {
        int bxp = bx - 17;                            // 0..1535
        int ds  = bxp & 3;                            // d-slice 0..3
        int rgid = bxp >> 2;                          // 0..383
        bool isQ = rgid < 192;
        int bb = isQ ? rgid : rgid - 192;
        int b  = bb / 96;
        int rg = bb % 96;                             // 4-row group
        const float* src = isQ ? q : k;
        int woff = isQ ? 0 : Dd * Hh;
        int rowbase = b * Lq + rg * 4;

        if (tid < 128) {
            int row = tid >> 5;
            int c4  = (tid & 31) << 2;
            *reinterpret_cast<float4*>(&tile[row][c4]) =
                *reinterpret_cast<const float4*>(
                    src + (size_t)(rowbase + row) * Dd + ds * 128 + c4);
        }
        __syncthreads();

        const float* wp = W1 + woff + (ds * 128) * Hh + tid;
        double a0 = 0.0, a1 = 0.0, a2 = 0.0, a3 = 0.0;
#pragma unroll 2
        for (int d4 = 0; d4 < 128; d4 += 4) {
            double w0 = (double)wp[(d4 + 0) * Hh];
            double w1 = (double)wp[(d4 + 1) * Hh];
            double w2 = (double)wp[(d4 + 2) * Hh];
            double w3 = (double)wp[(d4 + 3) * Hh];
            float4 t0 = *reinterpret_cast<const float4*>(&tile[0][d4]);
            float4 t1 = *reinterpret_cast<const float4*>(&tile[1][d4]);
            float4 t2 = *reinterpret_cast<const float4*>(&tile[2][d4]);
            float4 t3 = *reinterpret_cast<const float4*>(&tile[3][d4]);
            a0 = fma((double)t0.x, w0, a0); a0 = fma((double)t0.y, w1, a0);
            a0 = fma((double)t0.z, w2, a0); a0 = fma((double)t0.w, w3, a0);
            a1 = fma((double)t1.x, w0, a1); a1 = fma((double)t1.y, w1, a1);
            a1 = fma((double)t1.z, w2, a1); a1 = fma((double)t1.w, w3, a1);
            a2 = fma((double)t2.x, w0, a2); a2 = fma((double)t2.y, w1, a2);
            a2 = fma((double)t2.z, w2, a2); a2 = fma((double)t2.w, w3, a2);
            a3 = fma((double)t3.x, w0, a3); a3 = fma((double)t3.y, w1, a3);
            a3 = fma((double)t3.z, w2, a3); a3 = fma((double)t3.w, w3, a3);
        }
        int rowglob = (isQ ? 0 : Bb * Lq) + rowbase;
        size_t obase = ((size_t)rowglob * 4 + ds) * Hh + tid;
        part[obase]           = a0;
        part[obase + 4 * Hh]  = a1;
        part[obase + 8 * Hh]  = a2;
        part[obase + 12 * Hh] = a3;
    }
}

// ---------------------------------------------------------------------------
// finalize: sum the 4 d-slice partials (deterministic), add global dot;
// emit f64 hq_d/hk_d (cleanup) and f32 hq/hk (+b1 on q) for main.
__global__ __launch_bounds__(256) void finalize_kernel(
    const double* __restrict__ part,
    const double* __restrict__ gq_d, const double* __restrict__ gk_d,
    const float* __restrict__ b1,
    double* __restrict__ hq_d, double* __restrict__ hk_d,
    float* __restrict__ hq, float* __restrict__ hk)
{
    int tid = threadIdx.x;
    int bx  = blockIdx.x;
#pragma unroll
    for (int r = 0; r < 2; ++r) {
        int rowglob = bx * 2 + r;                     // 0..1535
        bool isQ = rowglob < Bb * Lq;
        int rr = isQ ? rowglob : rowglob - Bb * Lq;
        int b  = rr / Lq;
        size_t pbase = ((size_t)rowglob * 4) * Hh + tid;
        double p0 = part[pbase];
        double p1 = part[pbase + 1 * Hh];
        double p2 = part[pbase + 2 * Hh];
        double p3 = part[pbase + 3 * Hh];
        double gl = (isQ ? gq_d : gk_d)[b * Hh + tid];
        double tot = ((p0 + p1) + (p2 + p3)) + gl;
        size_t o = (size_t)rr * Hh + tid;
        if (isQ) {
            hq_d[o] = tot;
            hq[o]   = (float)(tot + (double)b1[tid]);
        } else {
            hk_d[o] = tot;
            hk[o]   = (float)tot;
        }
    }
}

// ---------------------------------------------------------------------------
// sim: 64x64 output tile, 4x4 per thread, TRANSPOSED LDS (d-major) so each
// dd needs only 2 ds_read_b128 for 16 FMAs (was 4 reads / 16 FMA).
// Split-K x8: block handles one 64-d slice; 8 partial planes; main sums.
// Pad 68: float4 rows stay 16B-aligned (272B row pitch); read-phase banks
// are broadcast/2-way (free), write-phase 8-way (~5% of compute).
__global__ __launch_bounds__(256) void sim_kernel(
    const float* __restrict__ q, const float* __restrict__ k,
    float* __restrict__ simP)
{
    __shared__ __align__(16) float qs_t[64][68];
    __shared__ __align__(16) float ks_t[64][68];
    int tid = threadIdx.x;
    int bx  = blockIdx.x;              // 0..575
    int kc  = bx / 72;                 // 0..7: 64-d slice
    int r   = bx % 72;
    int b   = r / 36;  r %= 36;
    int lt  = r / 6,  st = r % 6;

    const float* qb = q + (size_t)(b * Lq + lt * 64) * Dd + kc * 64;
    const float* kb = k + (size_t)(b * Sk + st * 64) * Dd + kc * 64;
#pragma unroll
    for (int it = 0; it < 4; ++it) {   // 64 rows x 16 float4 = 1024
        int i   = it * 256 + tid;
        int row = i >> 4;
        int c4  = (i & 15) << 2;
        float4 vq = *reinterpret_cast<const float4*>(qb + (size_t)row * Dd + c4);
        float4 vk = *reinterpret_cast<const float4*>(kb + (size_t)row * Dd + c4);
        qs_t[c4 + 0][row] = vq.x; qs_t[c4 + 1][row] = vq.y;
        qs_t[c4 + 2][row] = vq.z; qs_t[c4 + 3][row] = vq.w;
        ks_t[c4 + 0][row] = vk.x; ks_t[c4 + 1][row] = vk.y;
        ks_t[c4 + 2][row] = vk.z; ks_t[c4 + 3][row] = vk.w;
    }
    __syncthreads();

    int tl = tid >> 4, ts = tid & 15;
    float acc[4][4];
#pragma unroll
    for (int i = 0; i < 4; ++i)
#pragma unroll
        for (int j = 0; j < 4; ++j) acc[i][j] = 0.f;

#pragma unroll 4
    for (int dd = 0; dd < 64; ++dd) {
        float4 qa = *reinterpret_cast<const float4*>(&qs_t[dd][4 * tl]);
        float4 kb4 = *reinterpret_cast<const float4*>(&ks_t[dd][4 * ts]);
        acc[0][0] = fmaf(qa.x, kb4.x, acc[0][0]);
        acc[0][1] = fmaf(qa.x, kb4.y, acc[0][1]);
        acc[0][2] = fmaf(qa.x, kb4.z, acc[0][2]);
        acc[0][3] = fmaf(qa.x, kb4.w, acc[0][3]);
        acc[1][0] = fmaf(qa.y, kb4.x, acc[1][0]);
        acc[1][1] = fmaf(qa.y, kb4.y, acc[1][1]);
        acc[1][2] = fmaf(qa.y, kb4.z, acc[1][2]);
        acc[1][3] = fmaf(qa.y, kb4.w, acc[1][3]);
        acc[2][0] = fmaf(qa.z, kb4.x, acc[2][0]);
        acc[2][1] = fmaf(qa.z, kb4.y, acc[2][1]);
        acc[2][2] = fmaf(qa.z, kb4.z, acc[2][2]);
        acc[2][3] = fmaf(qa.z, kb4.w, acc[2][3]);
        acc[3][0] = fmaf(qa.w, kb4.x, acc[3][0]);
        acc[3][1] = fmaf(qa.w, kb4.y, acc[3][1]);
        acc[3][2] = fmaf(qa.w, kb4.z, acc[3][2]);
        acc[3][3] = fmaf(qa.w, kb4.w, acc[3][3]);
    }

    const float sc = 0.04419417382415922f;   // 1/sqrt(512)
    float* dst = simP + (size_t)kc * PLANE;
    int l0 = lt * 64 + 4 * tl, s0 = st * 64 + 4 * ts;
#pragma unroll
    for (int i = 0; i < 4; ++i) {
        float4 v = make_float4(acc[i][0] * sc, acc[i][1] * sc,
                               acc[i][2] * sc, acc[i][3] * sc);
        *reinterpret_cast<float4*>(&dst[(size_t)(b * Lq + l0 + i) * Sk + s0]) = v;
    }
}

// ---------------------------------------------------------------------------
// tanh-gelu pair accumulate: y2 = 2*gelu_tanh(x) = 2x*sigmoid(x*(K1+K2*x^2)).
__device__ __forceinline__ void gelu2t(float2 hqv, float2 hkv, float2 gwv,
                                       float2& s1, float2& s2, float2& sw)
{
    const float K1 = -2.30220815f;    // -2*log2(e)*sqrt(2/pi)
    const float K2 = -0.10294325f;    // K1 * 0.044715
    float xa = hqv.x + hkv.x,  xb = hqv.y + hkv.y;
    float x2a = xa * xa,       x2b = xb * xb;
    float pa = fmaf(K2, x2a, K1), pb = fmaf(K2, x2b, K1);
    float za = xa * pa,        zb = xb * pb;
    float ea = __builtin_amdgcn_exp2f(za);
    float eb = __builtin_amdgcn_exp2f(zb);
    float ra = __builtin_amdgcn_rcpf(1.0f + ea);
    float rb = __builtin_amdgcn_rcpf(1.0f + eb);
    float ya = (xa + xa) * ra, yb = (xb + xb) * rb;  // = 2*gelu
    s1.x += ya;                s1.y += yb;
    s2.x = fmaf(ya, ya, s2.x); s2.y = fmaf(yb, yb, s2.y);
    sw.x = fmaf(ya, gwv.x, sw.x); sw.y = fmaf(yb, gwv.y, sw.y);
}

// ---------------------------------------------------------------------------
// main: 32x16 (l,s) tile per 512-thread block; lane pair shares a 2-row
// output set split over h-halves; combine via __shfl_xor(.,1).
__global__ __launch_bounds__(512) void main_kernel(
    const float* __restrict__ hq, const float* __restrict__ hk,
    const float* __restrict__ simP,
    const float* __restrict__ gam, const float* __restrict__ W2,
    const float* __restrict__ scal,
    const float* __restrict__ gu, float* __restrict__ out,
    int* __restrict__ cnt, int* __restrict__ list)
{
    __shared__ __align__(16) float hq_t[32][260];
    __shared__ __align__(16) float hk_t[16][260];
    __shared__ __align__(16) float gw_s[256];
    int tid = threadIdx.x;
    int bx = blockIdx.x;
    int b  = bx / (12 * 24);
    int r  = bx % (12 * 24);
    int lt = r / 24, st = r % 24;          // l-tile 32 rows, s-tile 16 cols

    const float* hqb = hq + (b * Lq + lt * 32) * Hh;
    const float* hkb = hk + (b * Sk + st * 16) * Hh;
#pragma unroll
    for (int i = 0; i < 4; ++i) {          // 32 rows x 64 float4 = 2048
        int idx4 = i * 512 + tid;
        int row  = idx4 >> 6;
        int col4 = (idx4 & 63) << 2;
        *reinterpret_cast<float4*>(&hq_t[row][col4]) =
            *reinterpret_cast<const float4*>(hqb + row * Hh + col4);
    }
#pragma unroll
    for (int i = 0; i < 2; ++i) {          // 16 rows x 64 float4 = 1024
        int idx4 = i * 512 + tid;
        int row  = idx4 >> 6;
        int col4 = (idx4 & 63) << 2;
        *reinterpret_cast<float4*>(&hk_t[row][col4]) =
            *reinterpret_cast<const float4*>(hkb + row * Hh + col4);
    }
    if (tid < 256) gw_s[tid] = gam[tid] * W2[tid];
    __syncthreads();
    float gwsum  = scal[0];
    float bconst = scal[1];

    int opair = tid >> 1;                  // 0..255: output-pair id
    int hh    = tid & 1;                   // h-half
    int tl = opair >> 4, ts = opair & 15;

    float2 s1a = make_float2(0.f, 0.f), s2a = s1a, swa = s1a;
    float2 s1b = s1a, s2b = s1a, swb = s1a;
    int h0 = hh << 7;                      // 0 or 128
#pragma unroll 2
    for (int h4 = h0; h4 < h0 + 128; h4 += 4) {
        float4 ha = *reinterpret_cast<const float4*>(&hq_t[tl][h4]);
        float4 hb = *reinterpret_cast<const float4*>(&hq_t[tl + 16][h4]);
        float4 kk = *reinterpret_cast<const float4*>(&hk_t[ts][h4]);
        float4 g4 = *reinterpret_cast<const float4*>(&gw_s[h4]);
        gelu2t(make_float2(ha.x, ha.y), make_float2(kk.x, kk.y),
               make_float2(g4.x, g4.y), s1a, s2a, swa);
        gelu2t(make_float2(ha.z, ha.w), make_float2(kk.z, kk.w),
               make_float2(g4.z, g4.w), s1a, s2a, swa);
        gelu2t(make_float2(hb.x, hb.y), make_float2(kk.x, kk.y),
               make_float2(g4.x, g4.y), s1b, s2b, swb);
        gelu2t(make_float2(hb.z, hb.w), make_float2(kk.z, kk.w),
               make_float2(g4.z, g4.w), s1b, s2b, swb);
    }
    float S1a = s1a.x + s1a.y;  S1a += __shfl_xor(S1a, 1, 64);
    float S2a = s2a.x + s2a.y;  S2a += __shfl_xor(S2a, 1, 64);
    float SWa = swa.x + swa.y;  SWa += __shfl_xor(SWa, 1, 64);
    float S1b = s1b.x + s1b.y;  S1b += __shfl_xor(S1b, 1, 64);
    float S2b = s2b.x + s2b.y;  S2b += __shfl_xor(S2b, 1, 64);
    float SWb = swb.x + swb.y;  SWb += __shfl_xor(SWb, 1, 64);

    float S1 = hh ? S1b : S1a;
    float S2 = hh ? S2b : S2a;
    float SW = 0.5f * (hh ? SWb : SWa);
    float mu   = S1 * (1.0f / 512.0f);
    float var  = S2 * (1.0f / 1024.0f) - mu * mu;
    float rstd = rsqrtf(var + 1e-5f);
    float thr  = rstd * (SW - mu * gwsum) + bconst;

    int l = lt * 32 + tl + hh * 16, s = st * 16 + ts;
    int idx = (b * Lq + l) * Sk + s;
    float sv = 0.f;
#pragma unroll
    for (int p = 0; p < 8; ++p) sv += simP[(size_t)p * PLANE + idx];
    float2 uv = reinterpret_cast<const float2*>(gu)[idx];
    float u0 = fminf(fmaxf(uv.x, 1e-6f), 1.0f - 1e-6f);
    float u1 = fminf(fmaxf(uv.y, 1e-6f), 1.0f - 1e-6f);
    float g0 = -logf(-logf(u0));
    float g1 = -logf(-logf(u1));
    float t  = 0.2f * (sv - thr) + (g1 - g0);
    out[idx] = t > 0.0f ? 1.0f : 0.0f;
    if (fabsf(t) < 2e-3f) {
        int p = atomicAdd(cnt, 1);
        if (p < LIST_CAP) list[p] = idx;
    }
}

// ---------------------------------------------------------------------------
// cleanup: per flagged item, exact-f64 finish using precomputed projections.
__global__ __launch_bounds__(256) void cleanup_kernel(
    const float* __restrict__ q, const float* __restrict__ k,
    const double* __restrict__ hq_d, const double* __restrict__ hk_d,
    const float* __restrict__ b1,
    const float* __restrict__ gam, const float* __restrict__ bet,
    const float* __restrict__ W2, const float* __restrict__ b2,
    const float* __restrict__ gu, float* __restrict__ out,
    const int* __restrict__ cnt, const int* __restrict__ list)
{
    __shared__ double s0[256], s1[256], s2[256], s3[256];
    int tid = threadIdx.x;
    int n = *cnt;
    if (n > LIST_CAP) n = LIST_CAP;
    if (n == 0) return;

    double gw  = (double)gam[tid] * (double)W2[tid];
    double b1d = (double)b1[tid];
    s0[tid] = (double)bet[tid] * (double)W2[tid];
    s1[tid] = gw;
    __syncthreads();
    for (int o = 128; o > 0; o >>= 1) {
        if (tid < o) { s0[tid] += s0[tid + o]; s1[tid] += s1[tid + o]; }
        __syncthreads();
    }
    double bconst = s0[0] + (double)b2[0];
    double gwsum  = s1[0];
    __syncthreads();

    for (int it = blockIdx.x; it < n; it += gridDim.x) {
        int idx = list[it];
        int b   = idx / (Lq * Sk);
        int rem = idx % (Lq * Sk);
        int l = rem / Sk, s = rem % Sk;
        double x = (hq_d[(b * Lq + l) * Hh + tid]
                  + hk_d[(b * Sk + s) * Hh + tid]) + b1d;
        double y = 0.5 * x * (1.0 + erf(x * 0.70710678118654752440));
        const float* qrow = q + (b * Lq + l) * Dd;
        const float* krow = k + (b * Sk + s) * Dd;
        double sp = (double)qrow[tid] * (double)krow[tid]
                  + (double)qrow[tid + 256] * (double)krow[tid + 256];
        s0[tid] = y; s1[tid] = y * y; s2[tid] = y * gw; s3[tid] = sp;
        __syncthreads();
        for (int o = 128; o > 0; o >>= 1) {
            if (tid < o) {
                s0[tid] += s0[tid + o]; s1[tid] += s1[tid + o];
                s2[tid] += s2[tid + o]; s3[tid] += s3[tid + o];
            }
            __syncthreads();
        }
        if (tid == 0) {
            double mu   = s0[0] * (1.0 / 256.0);
            double var  = s1[0] * (1.0 / 256.0) - mu * mu;
            double rstd = 1.0 / sqrt(var + 1e-5);
            double thr  = rstd * (s2[0] - mu * gwsum) + bconst;
            double simv = s3[0] / 22.627416997969522;   // sqrt(512)
            float2 uv = reinterpret_cast<const float2*>(gu)[idx];
            double u0 = fmin(fmax((double)uv.x, 1e-6), 1.0 - 1e-6);
            double u1 = fmin(fmax((double)uv.y, 1e-6), 1.0 - 1e-6);
            double g0 = -log(-log(u0));
            double g1 = -log(-log(u1));
            double t  = 0.2 * (simv - thr) + (g1 - g0);
            out[idx] = t > 0.0 ? 1.0f : 0.0f;
        }
        __syncthreads();
    }
}

// ---------------------------------------------------------------------------
extern "C" void kernel_launch(void* const* d_in, const int* in_sizes, int n_in,
                              void* d_out, int out_size, void* d_ws, size_t ws_size,
                              hipStream_t stream)
{
    const float* q   = (const float*)d_in[0];
    const float* k   = (const float*)d_in[1];
    const float* qg  = (const float*)d_in[2];
    const float* kg  = (const float*)d_in[3];
    const float* W1  = (const float*)d_in[4];
    const float* b1  = (const float*)d_in[5];
    const float* gam = (const float*)d_in[6];
    const float* bet = (const float*)d_in[7];
    const float* W2  = (const float*)d_in[8];
    const float* b2  = (const float*)d_in[9];
    const float* gu  = (const float*)d_in[10];
    float* out = (float*)d_out;

    char*   ws   = (char*)d_ws;
    double* hq_d = (double*)(ws + HQD_OFF);
    double* hk_d = (double*)(ws + HKD_OFF);
    double* part = (double*)(ws + PART_OFF);
    double* gq_d = (double*)(ws + GQD_OFF);
    double* gk_d = (double*)(ws + GKD_OFF);
    float*  hq   = (float*)(ws + HQ_OFF);
    float*  hk   = (float*)(ws + HK_OFF);
    float*  simP = (float*)(ws + SIM_OFF);
    float*  scal = (float*)(ws + SCAL_OFF);
    int*    cnt  = (int*)(ws + CNT_OFF);
    int*    list = (int*)(ws + LIST_OFF);

    proj_fused_kernel<<<17 + NROWS, 256, 0, stream>>>(
        q, k, qg, kg, W1, gam, bet, W2, b2, gq_d, gk_d, scal, cnt, part);
    finalize_kernel<<<NROWS / 2, 256, 0, stream>>>(
        part, gq_d, gk_d, b1, hq_d, hk_d, hq, hk);
    sim_kernel<<<576, 256, 0, stream>>>(q, k, simP);
    main_kernel<<<Bb * 12 * 24, 512, 0, stream>>>(
        hq, hk, simP, gam, W2, scal, gu, out, cnt, list);
    cleanup_kernel<<<768, 256, 0, stream>>>(
        q, k, hq_d, hk_d, b1, gam, bet, W2, b2, gu, out, cnt, list);
}